// Round 4
// baseline (684.241 us; speedup 1.0000x reference)
//
#include <hip/hip_runtime.h>
#include <hip/hip_cooperative_groups.h>

namespace cg = cooperative_groups;

// Problem shape (fixed by setup_inputs): inputs [B=32, T=4096, F=256] fp32.
constexpr int B_ = 32;
constexpr int T_ = 4096;
constexpr int F_ = 256;
constexpr int F4 = F_ / 4;
constexpr int CHUNKS = 64;          // chunks along T
constexpr int L_ = T_ / CHUNKS;     // 64 timesteps per chunk
constexpr int ST = 8;               // timesteps per LDS slice (8 KB)
constexpr int NS = L_ / ST;         // 8 slices per chunk
constexpr int WPB = 4;              // waves (=chunks) per 256-thread block
constexpr int NBLK = (B_ * CHUNKS) / WPB;   // 512 = 256 CUs x 2 blocks/CU
constexpr float EPS_ = 1e-6f;

// ---- ordered-uint encoding for float atomic min/max (handles any sign) ----
__device__ __forceinline__ unsigned f2ord(float f) {
    unsigned u = __float_as_uint(f);
    return (u & 0x80000000u) ? ~u : (u | 0x80000000u);
}
__device__ __forceinline__ float ord2f(unsigned u) {
    return (u & 0x80000000u) ? __uint_as_float(u ^ 0x80000000u)
                             : __uint_as_float(~u);
}
__device__ __forceinline__ float clamp01(float v) {
    return fminf(fmaxf(v, 0.0f), 1.0f);
}

// ---- non-temporal float4 store via native clang vector type ----
typedef float __attribute__((ext_vector_type(4))) f32x4;
__device__ __forceinline__ void nt_store4(float4 v, float4* p) {
    f32x4 nv;
    nv.x = v.x; nv.y = v.y; nv.z = v.z; nv.w = v.w;
    __builtin_nontemporal_store(nv, reinterpret_cast<f32x4*>(p));
}

// ---- async global->LDS staging (16 B per lane; LDS dest is wave-uniform) ----
typedef const __attribute__((address_space(1))) unsigned GU;
typedef __attribute__((address_space(3))) unsigned LU;

__device__ __forceinline__ void async_row16(const float* g, float* l) {
    __builtin_amdgcn_global_load_lds((GU*)g, (LU*)l, 16, 0, 0);
}
__device__ __forceinline__ void issue_slice(const float* gbase, float* lbase,
                                            int lane) {
#pragma unroll
    for (int t = 0; t < ST; ++t)
        async_row16(gbase + (size_t)t * F_ + lane * 4, lbase + t * F_);
}
// Counted waits. vmcnt(8): everything except the 8 newest (= just-issued next
// slice) has retired -> current slice's DMA writes have landed in LDS.
__device__ __forceinline__ void wait_vm8() {
    asm volatile("s_waitcnt vmcnt(8)" ::: "memory");
    __builtin_amdgcn_sched_barrier(0);
}
__device__ __forceinline__ void wait_vm0() {
    asm volatile("s_waitcnt vmcnt(0)" ::: "memory");
    __builtin_amdgcn_sched_barrier(0);
}

#define EMA4(a, v)                    \
    a.x = fmaf(w, (v).x, d * a.x);    \
    a.y = fmaf(w, (v).y, d * a.y);    \
    a.z = fmaf(w, (v).z, d * a.z);    \
    a.w = fmaf(w, (v).w, d * a.w)

__device__ __forceinline__ float pcen_elem(float xv, float av, float g,
                                           float inv_r, float bias,
                                           float bpow) {
    const float p = __builtin_exp2f(-g * __builtin_log2f(EPS_ + av));
    const float base = fmaf(xv, p, bias);              // >= bias > 0
    return __builtin_exp2f(inv_r * __builtin_log2f(base)) - bpow;
}

// ===========================================================================
// Fused cooperative kernel: 4 phases separated by grid.sync().
//  P1: chunk-local zero-seeded EMA -> E               (x cold read, 128 MB)
//  P2: serial carry scan -> In (32 waves, ~4 us)
//  P3: seeded rescan + PCEN -> out (pre-norm) + global min/max atomics
//      (x re-read is L3-warm from P1)
//  P4: in-place affine normalize of each block's own region
//      (out re-read is L3-warm from P3; final store non-temporal)
// LDS 64 KB/block -> exactly 2 blocks/CU -> grid 512 is fully co-resident.
// ===========================================================================
__global__ __launch_bounds__(256) void pcen_fused(
        const float* __restrict__ x, const float* __restrict__ gain,
        const float* __restrict__ bias_p, const float* __restrict__ root,
        const float* __restrict__ smooth, float* __restrict__ out,
        float* __restrict__ E, float* __restrict__ In,
        unsigned* __restrict__ mm) {
    __shared__ float stage[WPB][2][ST * F_];
    __shared__ float red[2][WPB];
    cg::grid_group grid = cg::this_grid();

    const int wid  = threadIdx.x >> 6;
    const int lane = threadIdx.x & 63;
    const int bc   = blockIdx.x * WPB + wid;

    const float w = clamp01(smooth[0]);
    const float d = 1.0f - w;
    const float g = fminf(gain[0], 1.0f);
    const float r = fmaxf(root[0], 1.0f);
    const float inv_r = 1.0f / r;
    const float bias = bias_p[0];
    const float bpow = __builtin_exp2f(inv_r * __builtin_log2f(bias));
    const float* xc = x + (size_t)bc * L_ * F_;

    if (blockIdx.x == 0 && threadIdx.x == 0) {
        mm[0] = 0xFFFFFFFFu;  // ordered-min init (= +inf)
        mm[1] = 0x00000000u;  // ordered-max init (= -inf)
    }

    // ---------------- P1: chunk-local EMA, zero seed -> E ----------------
    issue_slice(xc, stage[wid][0], lane);
    float4 a = make_float4(0.f, 0.f, 0.f, 0.f);
    for (int s = 0; s < NS; ++s) {
        const int cb = s & 1;
        if (s + 1 < NS) {
            issue_slice(xc + (size_t)(s + 1) * ST * F_, stage[wid][cb ^ 1], lane);
            wait_vm8();
        } else {
            wait_vm0();
        }
        const float4* rows = reinterpret_cast<const float4*>(stage[wid][cb]);
#pragma unroll
        for (int t = 0; t < ST; ++t) {
            float4 v = rows[t * F4 + lane];
            EMA4(a, v);
        }
    }
    reinterpret_cast<float4*>(E + (size_t)bc * F_)[lane] = a;

    __threadfence();
    grid.sync();

    // ---------------- P2: cross-chunk carry scan -> In (32 waves) --------
    if (blockIdx.x < B_ / WPB) {
        const int b = bc;             // 0..31
        float dL = d;                 // d^64 via 6 squarings
        dL *= dL; dL *= dL; dL *= dL; dL *= dL; dL *= dL; dL *= dL;
        static_assert(L_ == 64, "dL squaring chain assumes L_ == 64");
        float4 cur = reinterpret_cast<const float4*>(
                         x + (size_t)b * T_ * F_)[lane];
        for (int c0 = 0; c0 < CHUNKS; c0 += 8) {
            float4 e[8];
#pragma unroll
            for (int i = 0; i < 8; ++i)
                e[i] = reinterpret_cast<const float4*>(E)[
                           ((size_t)b * CHUNKS + c0 + i) * F4 + lane];
#pragma unroll
            for (int i = 0; i < 8; ++i) {
                reinterpret_cast<float4*>(In)[
                    ((size_t)b * CHUNKS + c0 + i) * F4 + lane] = cur;
                cur.x = fmaf(dL, cur.x, e[i].x);
                cur.y = fmaf(dL, cur.y, e[i].y);
                cur.z = fmaf(dL, cur.z, e[i].z);
                cur.w = fmaf(dL, cur.w, e[i].w);
            }
        }
    }
    __threadfence();
    grid.sync();

    // ---------------- P3: seeded rescan + PCEN -> out(pre) + minmax ------
    a = reinterpret_cast<const float4*>(In)[(size_t)bc * F4 + lane];
    float4* oc = reinterpret_cast<float4*>(out + (size_t)bc * L_ * F_);
    issue_slice(xc, stage[wid][0], lane);
    float lmin = __builtin_inff(), lmax = -__builtin_inff();
    for (int s = 0; s < NS; ++s) {
        const int cb = s & 1;
        if (s + 1 < NS) {
            issue_slice(xc + (size_t)(s + 1) * ST * F_, stage[wid][cb ^ 1], lane);
            wait_vm8();
        } else {
            wait_vm0();
        }
        const float4* rows = reinterpret_cast<const float4*>(stage[wid][cb]);
#pragma unroll
        for (int t = 0; t < ST; ++t) {
            float4 v = rows[t * F4 + lane];
            EMA4(a, v);
            float4 o;
            o.x = pcen_elem(v.x, a.x, g, inv_r, bias, bpow);
            o.y = pcen_elem(v.y, a.y, g, inv_r, bias, bpow);
            o.z = pcen_elem(v.z, a.z, g, inv_r, bias, bpow);
            o.w = pcen_elem(v.w, a.w, g, inv_r, bias, bpow);
            lmin = fminf(lmin, fminf(fminf(o.x, o.y), fminf(o.z, o.w)));
            lmax = fmaxf(lmax, fmaxf(fmaxf(o.x, o.y), fmaxf(o.z, o.w)));
            oc[(size_t)(s * ST + t) * F4 + lane] = o;   // pre-norm; stays in L3
        }
    }
#pragma unroll
    for (int off = 32; off > 0; off >>= 1) {
        lmin = fminf(lmin, __shfl_xor(lmin, off));
        lmax = fmaxf(lmax, __shfl_xor(lmax, off));
    }
    if (lane == 0) { red[0][wid] = lmin; red[1][wid] = lmax; }
    __syncthreads();
    if (threadIdx.x == 0) {
        float bmin = red[0][0], bmax = red[1][0];
#pragma unroll
        for (int i = 1; i < WPB; ++i) {
            bmin = fminf(bmin, red[0][i]);
            bmax = fmaxf(bmax, red[1][i]);
        }
        atomicMin(&mm[0], f2ord(bmin));
        atomicMax(&mm[1], f2ord(bmax));
    }
    __threadfence();
    grid.sync();

    // ---------------- P4: in-place normalize of this block's region ------
    const float mn = ord2f(mm[0]);
    const float mx = ord2f(mm[1]);
    const float sc = 2.0f / (mx - mn);
    const float of = fmaf(-mn, sc, -1.0f);
    float4* po = reinterpret_cast<float4*>(out) +
                 (size_t)blockIdx.x * (WPB * L_ * F4);
    for (int i = threadIdx.x; i < WPB * L_ * F4; i += 256) {
        float4 v = po[i];                 // L3/L2-warm from P3
        v.x = fmaf(v.x, sc, of);
        v.y = fmaf(v.y, sc, of);
        v.z = fmaf(v.z, sc, of);
        v.w = fmaf(v.w, sc, of);
        nt_store4(v, &po[i]);             // final write, skip caches
    }
}

// ===========================================================================
// Fallback path (identical math, 4 separate launches) if cooperative launch
// is unavailable.
// ===========================================================================
__global__ __launch_bounds__(256) void ema_chunk_local(
        const float* __restrict__ x, const float* __restrict__ smooth,
        float* __restrict__ E, unsigned* __restrict__ mm) {
    __shared__ float stage[WPB][2][ST * F_];
    const int wid  = threadIdx.x >> 6;
    const int lane = threadIdx.x & 63;
    const int bc   = blockIdx.x * WPB + wid;
    if (blockIdx.x == 0 && threadIdx.x == 0) {
        mm[0] = 0xFFFFFFFFu; mm[1] = 0x00000000u;
    }
    const float w = clamp01(smooth[0]);
    const float d = 1.0f - w;
    const float* xc = x + (size_t)bc * L_ * F_;
    issue_slice(xc, stage[wid][0], lane);
    float4 a = make_float4(0.f, 0.f, 0.f, 0.f);
    for (int s = 0; s < NS; ++s) {
        const int cb = s & 1;
        if (s + 1 < NS) {
            issue_slice(xc + (size_t)(s + 1) * ST * F_, stage[wid][cb ^ 1], lane);
            wait_vm8();
        } else wait_vm0();
        const float4* rows = reinterpret_cast<const float4*>(stage[wid][cb]);
#pragma unroll
        for (int t = 0; t < ST; ++t) { float4 v = rows[t * F4 + lane]; EMA4(a, v); }
    }
    reinterpret_cast<float4*>(E + (size_t)bc * F_)[lane] = a;
}

__global__ __launch_bounds__(64) void ema_carry(
        const float* __restrict__ x, const float* __restrict__ smooth,
        const float* __restrict__ E, float* __restrict__ In) {
    const int b = blockIdx.x;
    const int lane = threadIdx.x;
    const float w = clamp01(smooth[0]);
    const float d = 1.0f - w;
    float dL = d;
    dL *= dL; dL *= dL; dL *= dL; dL *= dL; dL *= dL; dL *= dL;
    float4 cur = reinterpret_cast<const float4*>(x + (size_t)b * T_ * F_)[lane];
    for (int c0 = 0; c0 < CHUNKS; c0 += 8) {
        float4 e[8];
#pragma unroll
        for (int i = 0; i < 8; ++i)
            e[i] = reinterpret_cast<const float4*>(E)[
                       ((size_t)b * CHUNKS + c0 + i) * F4 + lane];
#pragma unroll
        for (int i = 0; i < 8; ++i) {
            reinterpret_cast<float4*>(In)[((size_t)b * CHUNKS + c0 + i) * F4 + lane] = cur;
            cur.x = fmaf(dL, cur.x, e[i].x);
            cur.y = fmaf(dL, cur.y, e[i].y);
            cur.z = fmaf(dL, cur.z, e[i].z);
            cur.w = fmaf(dL, cur.w, e[i].w);
        }
    }
}

__global__ __launch_bounds__(256) void pcen_minmax_out(
        const float* __restrict__ x, const float* __restrict__ In,
        const float* __restrict__ gain, const float* __restrict__ bias_p,
        const float* __restrict__ root, const float* __restrict__ smooth,
        float* __restrict__ out, unsigned* __restrict__ mm) {
    __shared__ float stage[WPB][2][ST * F_];
    __shared__ float red[2][WPB];
    const int wid  = threadIdx.x >> 6;
    const int lane = threadIdx.x & 63;
    const int bc   = blockIdx.x * WPB + wid;
    const float w = clamp01(smooth[0]);
    const float d = 1.0f - w;
    const float g = fminf(gain[0], 1.0f);
    const float r = fmaxf(root[0], 1.0f);
    const float inv_r = 1.0f / r;
    const float bias = bias_p[0];
    const float bpow = __builtin_exp2f(inv_r * __builtin_log2f(bias));
    const float* xc = x + (size_t)bc * L_ * F_;
    float4* oc = reinterpret_cast<float4*>(out + (size_t)bc * L_ * F_);
    float4 a = reinterpret_cast<const float4*>(In)[(size_t)bc * F4 + lane];
    issue_slice(xc, stage[wid][0], lane);
    float lmin = __builtin_inff(), lmax = -__builtin_inff();
    for (int s = 0; s < NS; ++s) {
        const int cb = s & 1;
        if (s + 1 < NS) {
            issue_slice(xc + (size_t)(s + 1) * ST * F_, stage[wid][cb ^ 1], lane);
            wait_vm8();
        } else wait_vm0();
        const float4* rows = reinterpret_cast<const float4*>(stage[wid][cb]);
#pragma unroll
        for (int t = 0; t < ST; ++t) {
            float4 v = rows[t * F4 + lane];
            EMA4(a, v);
            float4 o;
            o.x = pcen_elem(v.x, a.x, g, inv_r, bias, bpow);
            o.y = pcen_elem(v.y, a.y, g, inv_r, bias, bpow);
            o.z = pcen_elem(v.z, a.z, g, inv_r, bias, bpow);
            o.w = pcen_elem(v.w, a.w, g, inv_r, bias, bpow);
            lmin = fminf(lmin, fminf(fminf(o.x, o.y), fminf(o.z, o.w)));
            lmax = fmaxf(lmax, fmaxf(fmaxf(o.x, o.y), fmaxf(o.z, o.w)));
            oc[(size_t)(s * ST + t) * F4 + lane] = o;
        }
    }
#pragma unroll
    for (int off = 32; off > 0; off >>= 1) {
        lmin = fminf(lmin, __shfl_xor(lmin, off));
        lmax = fmaxf(lmax, __shfl_xor(lmax, off));
    }
    if (lane == 0) { red[0][wid] = lmin; red[1][wid] = lmax; }
    __syncthreads();
    if (threadIdx.x == 0) {
        float bmin = red[0][0], bmax = red[1][0];
#pragma unroll
        for (int i = 1; i < WPB; ++i) {
            bmin = fminf(bmin, red[0][i]);
            bmax = fmaxf(bmax, red[1][i]);
        }
        atomicMin(&mm[0], f2ord(bmin));
        atomicMax(&mm[1], f2ord(bmax));
    }
}

__global__ __launch_bounds__(256) void norm_apply(
        float* __restrict__ out, const unsigned* __restrict__ mm, int n4) {
    const float mn = ord2f(mm[0]);
    const float mx = ord2f(mm[1]);
    const float s = 2.0f / (mx - mn);
    const float o = fmaf(-mn, s, -1.0f);
    float4* p = reinterpret_cast<float4*>(out);
    const int stride = gridDim.x * blockDim.x;
    for (int i = blockIdx.x * blockDim.x + threadIdx.x; i < n4; i += stride) {
        float4 v = p[i];
        v.x = fmaf(v.x, s, o);
        v.y = fmaf(v.y, s, o);
        v.z = fmaf(v.z, s, o);
        v.w = fmaf(v.w, s, o);
        nt_store4(v, &p[i]);
    }
}

extern "C" void kernel_launch(void* const* d_in, const int* in_sizes, int n_in,
                              void* d_out, int out_size, void* d_ws, size_t ws_size,
                              hipStream_t stream) {
    const float* x      = (const float*)d_in[0];
    const float* gain   = (const float*)d_in[1];
    const float* bias   = (const float*)d_in[2];
    const float* root   = (const float*)d_in[3];
    const float* smooth = (const float*)d_in[4];
    float* out = (float*)d_out;

    // ws layout: E [B*CHUNKS*F] | In [B*CHUNKS*F] | mm[2]  (~4 MiB + 8 B)
    float* E  = (float*)d_ws;
    float* In = E + (size_t)B_ * CHUNKS * F_;
    unsigned* mm = (unsigned*)(In + (size_t)B_ * CHUNKS * F_);

    void* args[] = {(void*)&x, (void*)&gain, (void*)&bias, (void*)&root,
                    (void*)&smooth, (void*)&out, (void*)&E, (void*)&In,
                    (void*)&mm};
    hipError_t err = hipLaunchCooperativeKernel(
        (const void*)pcen_fused, dim3(NBLK), dim3(256), args, 0, stream);
    if (err != hipSuccess) {
        // Fallback: identical math via 4 launches.
        ema_chunk_local<<<NBLK, 256, 0, stream>>>(x, smooth, E, mm);
        ema_carry<<<B_, 64, 0, stream>>>(x, smooth, E, In);
        pcen_minmax_out<<<NBLK, 256, 0, stream>>>(x, In, gain, bias, root,
                                                  smooth, out, mm);
        norm_apply<<<2048, 256, 0, stream>>>(out, mm, (B_ * T_ * F_) / 4);
    }
}

// Round 5
// 326.227 us; speedup vs baseline: 2.0974x; 2.0974x over previous
//
#include <hip/hip_runtime.h>

// Problem shape (fixed by setup_inputs): inputs [B=32, T=4096, F=256] fp32.
constexpr int B_ = 32;
constexpr int T_ = 4096;
constexpr int F_ = 256;
constexpr int F4 = F_ / 4;
constexpr int CHUNKS = 256;              // chunks along T (16-KB chunks)
constexpr int L_ = T_ / CHUNKS;          // 16 timesteps per chunk
constexpr int ST = 8;                    // timesteps per LDS slice (8 KB)
constexpr int SPC = L_ / ST;             // 2 slices per chunk
constexpr int WPB = 4;                   // waves per 256-thread block
constexpr int NBLK = 512;                // 2 blocks/CU (64-KB LDS) -> resident
constexpr int NWAVES = NBLK * WPB;       // 2048 concurrent waves
constexpr int TOTCH = B_ * CHUNKS;       // 8192 chunks
constexpr int CPW = TOTCH / NWAVES;      // 4 chunks per wave
constexpr int NSL = CPW * SPC;           // 8 slices per wave
constexpr float EPS_ = 1e-6f;

// Concurrency layout: wave w handles chunks c_glob = j*NWAVES + w (j=0..3).
// At any instant all resident waves read a CONTIGUOUS ~32-MB window of x
// (chunk bases step 16 KB across the grid), so every HBM channel / L3 slice
// is active — unlike the old 64-KB-strided lockstep layout (~1 TB/s).

// ---- ordered-uint encoding for float atomic min/max (handles any sign) ----
__device__ __forceinline__ unsigned f2ord(float f) {
    unsigned u = __float_as_uint(f);
    return (u & 0x80000000u) ? ~u : (u | 0x80000000u);
}
__device__ __forceinline__ float ord2f(unsigned u) {
    return (u & 0x80000000u) ? __uint_as_float(u ^ 0x80000000u)
                             : __uint_as_float(~u);
}
__device__ __forceinline__ float clamp01(float v) {
    return fminf(fmaxf(v, 0.0f), 1.0f);
}

// ---- async global->LDS staging (16 B per lane; LDS dest is wave-uniform) ----
typedef const __attribute__((address_space(1))) unsigned GU;
typedef __attribute__((address_space(3))) unsigned LU;

__device__ __forceinline__ void async_row16(const float* g, float* l) {
    __builtin_amdgcn_global_load_lds((GU*)g, (LU*)l, 16, 0, 0);
}
__device__ __forceinline__ void issue_slice(const float* gbase, float* lbase,
                                            int lane) {
#pragma unroll
    for (int t = 0; t < ST; ++t)
        async_row16(gbase + (size_t)t * F_ + lane * 4, lbase + t * F_);
}
// vmcnt retires in ISSUE order, so a counted wait of N leaves the N newest
// VMEM ops (next-slice loads and/or recent stores) in flight.
__device__ __forceinline__ void wait_vm8() {
    asm volatile("s_waitcnt vmcnt(8)" ::: "memory");
    __builtin_amdgcn_sched_barrier(0);
}
__device__ __forceinline__ void wait_vm16() {
    asm volatile("s_waitcnt vmcnt(16)" ::: "memory");
    __builtin_amdgcn_sched_barrier(0);
}
__device__ __forceinline__ void wait_vm0() {
    asm volatile("s_waitcnt vmcnt(0)" ::: "memory");
    __builtin_amdgcn_sched_barrier(0);
}

#define EMA4(a, v)                    \
    a.x = fmaf(w, (v).x, d * a.x);    \
    a.y = fmaf(w, (v).y, d * a.y);    \
    a.z = fmaf(w, (v).z, d * a.z);    \
    a.w = fmaf(w, (v).w, d * a.w)

__device__ __forceinline__ float pcen_elem(float xv, float av, float g,
                                           float inv_r, float bias,
                                           float bpow) {
    const float p = __builtin_exp2f(-g * __builtin_log2f(EPS_ + av));
    const float base = fmaf(xv, p, bias);              // >= bias > 0
    return __builtin_exp2f(inv_r * __builtin_log2f(base)) - bpow;
}

// slice s of wave w64: chunk j = s/SPC at c_glob = j*NWAVES + w64,
// intra-chunk timestep offset (s%SPC)*ST.
__device__ __forceinline__ const float* slice_src(const float* x, int s,
                                                  int w64) {
    const int cg = (s >> 1) * NWAVES + w64;      // SPC == 2
    return x + ((size_t)cg * L_ + (s & 1) * ST) * F_;
}

// ---------------------------------------------------------------------------
// Kernel A: chunk-local EMA with zero seed; emit end-state E[c_glob][f].
// Grid-stride chunk order; LDS double-buffered slice pipeline.
// ---------------------------------------------------------------------------
__global__ __launch_bounds__(256) void ema_chunk_local(
        const float* __restrict__ x, const float* __restrict__ smooth,
        float* __restrict__ E, unsigned* __restrict__ mm) {
    __shared__ float stage[WPB][2][ST * F_];
    const int wid  = threadIdx.x >> 6;
    const int lane = threadIdx.x & 63;
    const int w64  = blockIdx.x * WPB + wid;
    if (blockIdx.x == 0 && threadIdx.x == 0) {
        mm[0] = 0xFFFFFFFFu;  // ordered-min init (= +inf)
        mm[1] = 0x00000000u;  // ordered-max init (= -inf)
    }
    const float w = clamp01(smooth[0]);
    const float d = 1.0f - w;

    issue_slice(slice_src(x, 0, w64), stage[wid][0], lane);
    float4 a = make_float4(0.f, 0.f, 0.f, 0.f);
    for (int s = 0; s < NSL; ++s) {
        if (s + 1 < NSL) {
            issue_slice(slice_src(x, s + 1, w64), stage[wid][(s + 1) & 1], lane);
            wait_vm8();              // oldest 8 (current slice) have landed
        } else {
            wait_vm0();
        }
        const float4* rows = reinterpret_cast<const float4*>(stage[wid][s & 1]);
#pragma unroll
        for (int t = 0; t < ST; ++t) {
            float4 v = rows[t * F4 + lane];
            EMA4(a, v);
        }
        if (s & 1) {                 // chunk finished (2 slices per chunk)
            const int cg = (s >> 1) * NWAVES + w64;
            reinterpret_cast<float4*>(E)[(size_t)cg * F4 + lane] = a;
            a = make_float4(0.f, 0.f, 0.f, 0.f);
        }
    }
}

// ---------------------------------------------------------------------------
// Kernel B: cross-chunk carry scan, serial in c per batch b.
// In_0 = x[b,0,f]; In_c = d^L * In_{c-1} + E_{c-1}. 8-deep batched prefetch.
// ---------------------------------------------------------------------------
__global__ __launch_bounds__(64) void ema_carry(
        const float* __restrict__ x, const float* __restrict__ smooth,
        const float* __restrict__ E, float* __restrict__ In) {
    const int b = blockIdx.x;
    const int lane = threadIdx.x;
    const float w = clamp01(smooth[0]);
    const float d = 1.0f - w;
    float dL = d;                    // d^16 via 4 squarings
    dL *= dL; dL *= dL; dL *= dL; dL *= dL;
    static_assert(L_ == 16, "dL squaring chain assumes L_ == 16");

    float4 cur = reinterpret_cast<const float4*>(x + (size_t)b * T_ * F_)[lane];
    for (int c0 = 0; c0 < CHUNKS; c0 += 8) {
        float4 e[8];
#pragma unroll
        for (int i = 0; i < 8; ++i)
            e[i] = reinterpret_cast<const float4*>(E)[
                       ((size_t)b * CHUNKS + c0 + i) * F4 + lane];
#pragma unroll
        for (int i = 0; i < 8; ++i) {
            reinterpret_cast<float4*>(In)[
                ((size_t)b * CHUNKS + c0 + i) * F4 + lane] = cur;
            cur.x = fmaf(dL, cur.x, e[i].x);
            cur.y = fmaf(dL, cur.y, e[i].y);
            cur.z = fmaf(dL, cur.z, e[i].z);
            cur.w = fmaf(dL, cur.w, e[i].w);
        }
    }
}

// ---------------------------------------------------------------------------
// Kernel C: seeded re-scan + PCEN -> out (pre-norm) + global min/max.
// Same grid-stride chunk order as A. wait_vm16 leaves the 8 out-stores of the
// previous slice plus the 8 next-slice loads in flight (in-order retirement).
// ---------------------------------------------------------------------------
__global__ __launch_bounds__(256) void pcen_minmax_out(
        const float* __restrict__ x, const float* __restrict__ In,
        const float* __restrict__ gain, const float* __restrict__ bias_p,
        const float* __restrict__ root, const float* __restrict__ smooth,
        float* __restrict__ out, unsigned* __restrict__ mm) {
    __shared__ float stage[WPB][2][ST * F_];
    __shared__ float red[2][WPB];
    const int wid  = threadIdx.x >> 6;
    const int lane = threadIdx.x & 63;
    const int w64  = blockIdx.x * WPB + wid;
    const float w = clamp01(smooth[0]);
    const float d = 1.0f - w;
    const float g = fminf(gain[0], 1.0f);
    const float r = fmaxf(root[0], 1.0f);
    const float inv_r = 1.0f / r;
    const float bias = bias_p[0];
    const float bpow = __builtin_exp2f(inv_r * __builtin_log2f(bias));

    issue_slice(slice_src(x, 0, w64), stage[wid][0], lane);
    float4 a = make_float4(0.f, 0.f, 0.f, 0.f);
    float lmin = __builtin_inff(), lmax = -__builtin_inff();
    for (int s = 0; s < NSL; ++s) {
        const int cg = (s >> 1) * NWAVES + w64;
        if ((s & 1) == 0)            // chunk start: load carry seed
            a = reinterpret_cast<const float4*>(In)[(size_t)cg * F4 + lane];
        if (s + 1 < NSL) {
            issue_slice(slice_src(x, s + 1, w64), stage[wid][(s + 1) & 1], lane);
            if (s == 0) wait_vm8(); else wait_vm16();
        } else {
            wait_vm0();
        }
        const float4* rows = reinterpret_cast<const float4*>(stage[wid][s & 1]);
        float4* oc = reinterpret_cast<float4*>(out) +
                     ((size_t)cg * L_ + (s & 1) * ST) * F4 + lane;
#pragma unroll
        for (int t = 0; t < ST; ++t) {
            float4 v = rows[t * F4 + lane];
            EMA4(a, v);
            float4 o;
            o.x = pcen_elem(v.x, a.x, g, inv_r, bias, bpow);
            o.y = pcen_elem(v.y, a.y, g, inv_r, bias, bpow);
            o.z = pcen_elem(v.z, a.z, g, inv_r, bias, bpow);
            o.w = pcen_elem(v.w, a.w, g, inv_r, bias, bpow);
            lmin = fminf(lmin, fminf(fminf(o.x, o.y), fminf(o.z, o.w)));
            lmax = fmaxf(lmax, fmaxf(fmaxf(o.x, o.y), fmaxf(o.z, o.w)));
            oc[(size_t)t * F4] = o;  // pre-norm out
        }
    }
#pragma unroll
    for (int off = 32; off > 0; off >>= 1) {
        lmin = fminf(lmin, __shfl_xor(lmin, off));
        lmax = fmaxf(lmax, __shfl_xor(lmax, off));
    }
    if (lane == 0) { red[0][wid] = lmin; red[1][wid] = lmax; }
    __syncthreads();
    if (threadIdx.x == 0) {
        float bmin = red[0][0], bmax = red[1][0];
#pragma unroll
        for (int i = 1; i < WPB; ++i) {
            bmin = fminf(bmin, red[0][i]);
            bmax = fmaxf(bmax, red[1][i]);
        }
        atomicMin(&mm[0], f2ord(bmin));
        atomicMax(&mm[1], f2ord(bmax));
    }
}

// ---------------------------------------------------------------------------
// Kernel D: in-place global min/max normalization (flat grid-stride sweep —
// measured ~5-6 TB/s; do NOT block-chunk this, see round-4 post-mortem).
// ---------------------------------------------------------------------------
__global__ __launch_bounds__(256) void norm_apply(
        float* __restrict__ out, const unsigned* __restrict__ mm, int n4) {
    const float mn = ord2f(mm[0]);
    const float mx = ord2f(mm[1]);
    const float s = 2.0f / (mx - mn);
    const float o = fmaf(-mn, s, -1.0f);
    float4* p = reinterpret_cast<float4*>(out);
    const int stride = gridDim.x * blockDim.x;
    for (int i = blockIdx.x * blockDim.x + threadIdx.x; i < n4; i += stride) {
        float4 v = p[i];
        v.x = fmaf(v.x, s, o);
        v.y = fmaf(v.y, s, o);
        v.z = fmaf(v.z, s, o);
        v.w = fmaf(v.w, s, o);
        p[i] = v;
    }
}

extern "C" void kernel_launch(void* const* d_in, const int* in_sizes, int n_in,
                              void* d_out, int out_size, void* d_ws, size_t ws_size,
                              hipStream_t stream) {
    const float* x      = (const float*)d_in[0];
    const float* gain   = (const float*)d_in[1];
    const float* bias   = (const float*)d_in[2];
    const float* root   = (const float*)d_in[3];
    const float* smooth = (const float*)d_in[4];
    float* out = (float*)d_out;

    // ws layout: E [TOTCH*F] | In [TOTCH*F] | mm[2]   (16 MiB + 8 B)
    float* E  = (float*)d_ws;
    float* In = E + (size_t)TOTCH * F_;
    unsigned* mm = (unsigned*)(In + (size_t)TOTCH * F_);

    ema_chunk_local<<<NBLK, 256, 0, stream>>>(x, smooth, E, mm);
    ema_carry<<<B_, 64, 0, stream>>>(x, smooth, E, In);
    pcen_minmax_out<<<NBLK, 256, 0, stream>>>(x, In, gain, bias, root, smooth,
                                              out, mm);
    norm_apply<<<2048, 256, 0, stream>>>(out, mm, (B_ * T_ * F_) / 4);
}